// Round 1
// baseline (311.327 us; speedup 1.0000x reference)
//
#include <hip/hip_runtime.h>
#include <hip/hip_bf16.h>

// Problem: B=4, T=2048, C=1024. Single-head causal attention, fp32 in/out.
// Strategy: bf16 MFMA for all three matmul stages, fp32 softmax.

typedef short bf16x8 __attribute__((ext_vector_type(8)));
typedef float f32x4  __attribute__((ext_vector_type(4)));

#define T_SEQ 2048
#define EMB   1024
#define NBAT  4

// ---------------------------------------------------------------- cast f32 -> bf16
struct alignas(8) bh4 { __hip_bfloat16 a, b, c, d; };

__global__ void cast_f32_bf16_x4(const float* __restrict__ src,
                                 __hip_bfloat16* __restrict__ dst, int n4) {
    int i = blockIdx.x * blockDim.x + threadIdx.x;
    if (i >= n4) return;
    float4 v = reinterpret_cast<const float4*>(src)[i];
    bh4 o { __float2bfloat16(v.x), __float2bfloat16(v.y),
            __float2bfloat16(v.z), __float2bfloat16(v.w) };
    reinterpret_cast<bh4*>(dst)[i] = o;
}

// ---------------------------------------------------------------- gemm_bt
// C[M,N] = A[M,K] * B[N,K]^T   (both A and B row-major with K contiguous)
// 128x128 tile per block (256 threads = 4 waves, each wave 64x64 = 4x4 MFMA tiles)
// OUT_BF16: write bf16 else fp32.  CSKIP: skip tiles strictly above diagonal.
// KBOUND: K-loop runs to (row_tile+1)*128 (causal PV).
__device__ __forceinline__ void load_lds16(const void* g, void* l) {
    __builtin_amdgcn_global_load_lds(
        (const __attribute__((address_space(1))) void*)g,
        (__attribute__((address_space(3))) void*)l, 16, 0, 0);
}

template<int OUT_BF16, int CSKIP, int KBOUND>
__global__ __launch_bounds__(256) void gemm_bt(
    const __hip_bfloat16* __restrict__ Abase,
    const __hip_bfloat16* __restrict__ Bbase,
    void* __restrict__ Cbase,
    int K, int lda, int ldb, int ldc,
    long batchA, long batchB, long batchC)
{
    const int ct = blockIdx.x;   // col tile (N/128)
    const int rt = blockIdx.y;   // row tile (M/128)
    const int bz = blockIdx.z;   // batch
    if (CSKIP && ct > rt) return;
    const int k_len = KBOUND ? (rt + 1) * 128 : K;

    const short* A = (const short*)Abase + bz * batchA + (long)rt * 128 * lda;
    const short* B = (const short*)Bbase + bz * batchB + (long)ct * 128 * ldb;

    __shared__ short lsA[128 * 32];
    __shared__ short lsB[128 * 32];

    const int tid  = threadIdx.x;
    const int wave = tid >> 6;
    const int lane = tid & 63;
    const int wr   = (wave >> 1) * 64;   // wave row offset in 128-tile
    const int wc   = (wave &  1) * 64;   // wave col offset

    // staging: wave w loads tile rows [w*32, w*32+32); lane i -> row += i>>2, col (i&3)*8
    const int srow = wave * 32 + (lane >> 2);
    const int scol = (lane & 3) * 8;

    // fragment addressing (16x16x32): A[m = lane&15][k = (lane>>4)*8 + j]
    const int frow = lane & 15;
    const int fk   = (lane >> 4) * 8;

    f32x4 acc[4][4] = {};

    for (int k0 = 0; k0 < k_len; k0 += 32) {
        const short* ga = A + (long)srow * lda + k0 + scol;
        const short* gb = B + (long)srow * ldb + k0 + scol;
        load_lds16(ga,             &lsA[(wave * 32) * 32]);
        load_lds16(ga + 16L * lda, &lsA[(wave * 32 + 16) * 32]);
        load_lds16(gb,             &lsB[(wave * 32) * 32]);
        load_lds16(gb + 16L * ldb, &lsB[(wave * 32 + 16) * 32]);
        __syncthreads();   // compiler emits s_waitcnt vmcnt(0) before s_barrier

        bf16x8 af[4], bfr[4];
        #pragma unroll
        for (int m = 0; m < 4; ++m)
            af[m] = *(const bf16x8*)&lsA[(wr + m * 16 + frow) * 32 + fk];
        #pragma unroll
        for (int n = 0; n < 4; ++n)
            bfr[n] = *(const bf16x8*)&lsB[(wc + n * 16 + frow) * 32 + fk];
        #pragma unroll
        for (int m = 0; m < 4; ++m)
            #pragma unroll
            for (int n = 0; n < 4; ++n)
                acc[m][n] = __builtin_amdgcn_mfma_f32_16x16x32_bf16(
                    af[m], bfr[n], acc[m][n], 0, 0, 0);
        __syncthreads();
    }

    // epilogue: C/D layout col = lane&15, row = (lane>>4)*4 + reg
    const long crow0 = (long)rt * 128 + wr;
    const long ccol0 = (long)ct * 128 + wc;
    const int  orow  = (lane >> 4) * 4;
    const int  ocol  = lane & 15;

    if (OUT_BF16) {
        __hip_bfloat16* C = (__hip_bfloat16*)Cbase + bz * batchC;
        #pragma unroll
        for (int m = 0; m < 4; ++m)
            #pragma unroll
            for (int n = 0; n < 4; ++n)
                #pragma unroll
                for (int r = 0; r < 4; ++r)
                    C[(crow0 + m * 16 + orow + r) * ldc + ccol0 + n * 16 + ocol] =
                        __float2bfloat16(acc[m][n][r]);
    } else {
        float* C = (float*)Cbase + bz * batchC;
        #pragma unroll
        for (int m = 0; m < 4; ++m)
            #pragma unroll
            for (int n = 0; n < 4; ++n)
                #pragma unroll
                for (int r = 0; r < 4; ++r)
                    C[(crow0 + m * 16 + orow + r) * ldc + ccol0 + n * 16 + ocol] =
                        acc[m][n][r];
    }
}

// ---------------------------------------------------------------- V transpose
// V: [B*T][EMB] bf16  ->  vT: [B][EMB][T] bf16
__global__ void transpose_v(const __hip_bfloat16* __restrict__ V,
                            __hip_bfloat16* __restrict__ vT) {
    __shared__ __hip_bfloat16 tile[64][65];
    const int b  = blockIdx.z;
    const int t0 = blockIdx.x * 64;
    const int d0 = blockIdx.y * 64;
    const int tid = threadIdx.x;           // 256
    const int c  = tid & 63;
    const int r4 = tid >> 6;               // 0..3
    #pragma unroll
    for (int i = 0; i < 16; ++i) {
        int row = r4 + i * 4;              // 0..63 (t-local)
        tile[row][c] = V[(size_t)(b * T_SEQ + t0 + row) * EMB + d0 + c];
    }
    __syncthreads();
    #pragma unroll
    for (int i = 0; i < 16; ++i) {
        int drow = r4 + i * 4;             // 0..63 (d-local)
        vT[((size_t)b * EMB + d0 + drow) * T_SEQ + t0 + c] = tile[c][drow];
    }
}

// ---------------------------------------------------------------- causal softmax
// In-place: reads fp32 S row (8KB), writes bf16 P into the first 4KB of the
// same row region (row stride stays 8KB => no cross-row aliasing).
__device__ __forceinline__ float waveMax(float v) {
    #pragma unroll
    for (int o = 32; o; o >>= 1) v = fmaxf(v, __shfl_xor(v, o));
    return v;
}
__device__ __forceinline__ float waveSum(float v) {
    #pragma unroll
    for (int o = 32; o; o >>= 1) v += __shfl_xor(v, o);
    return v;
}

__global__ void softmax_causal(float* __restrict__ Sbuf) {
    const int r = blockIdx.x;              // 0 .. B*T-1
    const int t = r & (T_SEQ - 1);
    float* srow = Sbuf + (size_t)r * T_SEQ;
    const float scale = 0.03125f;          // 1024^-0.5
    const int tid  = threadIdx.x;          // 256
    const int wave = tid >> 6;
    const int lane = tid & 63;
    __shared__ float red[4];

    float vals[8];
    float mx = -INFINITY;
    #pragma unroll
    for (int i = 0; i < 8; ++i) {
        int s = tid + i * 256;
        float v = (s <= t) ? srow[s] * scale : -INFINITY;
        vals[i] = v;
        mx = fmaxf(mx, v);
    }
    mx = waveMax(mx);
    if (lane == 0) red[wave] = mx;
    __syncthreads();
    mx = fmaxf(fmaxf(red[0], red[1]), fmaxf(red[2], red[3]));
    __syncthreads();

    float sum = 0.f;
    #pragma unroll
    for (int i = 0; i < 8; ++i) {
        float e = __expf(vals[i] - mx);    // exp(-inf - mx) = 0
        vals[i] = e;
        sum += e;
    }
    sum = waveSum(sum);
    if (lane == 0) red[wave] = sum;
    __syncthreads();
    sum = red[0] + red[1] + red[2] + red[3];
    const float inv = 1.f / sum;

    const int kend = ((t >> 7) + 1) << 7;  // round_up(t+1, 128)
    __hip_bfloat16* prow = (__hip_bfloat16*)srow;
    #pragma unroll
    for (int i = 0; i < 8; ++i) {
        int s = tid + i * 256;
        if (s < kend) prow[s] = __float2bfloat16(vals[i] * inv);
    }
}

// ---------------------------------------------------------------- launch
extern "C" void kernel_launch(void* const* d_in, const int* in_sizes, int n_in,
                              void* d_out, int out_size, void* d_ws, size_t ws_size,
                              hipStream_t stream) {
    const float* x  = (const float*)d_in[0];
    const float* Wq = (const float*)d_in[1];
    const float* Wk = (const float*)d_in[2];
    const float* Wv = (const float*)d_in[3];

    char* ws = (char*)d_ws;
    // workspace layout (bytes):
    //   xb  @ 0         : 8192*1024*2      = 16,777,216
    //   wb  @ 16777216  : 3*1024*1024*2    =  6,291,456
    //   qkv @ 23068672  : 3*8192*1024*2    = 50,331,648
    //   vT  @ 73400320  : 4*1024*2048*2    = 16,777,216
    //   S   @ 90177536  : 4*2048*2048*4    = 67,108,864   (P bf16 aliases S rows)
    // total 157,286,400
    __hip_bfloat16* xb  = (__hip_bfloat16*)(ws);
    __hip_bfloat16* wb  = (__hip_bfloat16*)(ws + 16777216);
    __hip_bfloat16* qkv = (__hip_bfloat16*)(ws + 23068672);
    __hip_bfloat16* vT  = (__hip_bfloat16*)(ws + 73400320);
    float*          S   = (float*)        (ws + 90177536);

    // 1) casts
    cast_f32_bf16_x4<<<dim3(2097152 / 256), 256, 0, stream>>>(x, xb, 2097152);
    cast_f32_bf16_x4<<<dim3(262144 / 256), 256, 0, stream>>>(Wq, wb,            262144);
    cast_f32_bf16_x4<<<dim3(262144 / 256), 256, 0, stream>>>(Wk, wb + 1048576,  262144);
    cast_f32_bf16_x4<<<dim3(262144 / 256), 256, 0, stream>>>(Wv, wb + 2097152,  262144);

    // 2) Q,K,V = x @ W^T   (batched over the 3 weight matrices)
    gemm_bt<1, 0, 0><<<dim3(8, 64, 3), 256, 0, stream>>>(
        xb, wb, qkv,
        /*K*/1024, /*lda*/1024, /*ldb*/1024, /*ldc*/1024,
        /*bA*/0L, /*bB*/1048576L, /*bC*/8388608L);

    // 3) V^T per batch
    transpose_v<<<dim3(32, 16, 4), 256, 0, stream>>>(qkv + 2 * 8388608L, vT);

    // 4) S = Q @ K^T  (per batch, skip above-diagonal tiles)
    gemm_bt<0, 1, 0><<<dim3(16, 16, 4), 256, 0, stream>>>(
        qkv, qkv + 8388608L, S,
        /*K*/1024, /*lda*/1024, /*ldb*/1024, /*ldc*/2048,
        /*bA*/2097152L, /*bB*/2097152L, /*bC*/4194304L);

    // 5) P = softmax(mask(S/32)), bf16 in place (row stride 4096 elements)
    softmax_causal<<<dim3(NBAT * T_SEQ), 256, 0, stream>>>(S);

    // 6) O = P @ V   (B^T operand = vT; causal K-bound)
    gemm_bt<0, 0, 1><<<dim3(8, 16, 4), 256, 0, stream>>>(
        (const __hip_bfloat16*)S, vT, d_out,
        /*K*/2048, /*lda*/4096, /*ldb*/2048, /*ldc*/1024,
        /*bA*/8388608L, /*bB*/2097152L, /*bC*/2097152L);
}

// Round 2
// 287.596 us; speedup vs baseline: 1.0825x; 1.0825x over previous
//
#include <hip/hip_runtime.h>
#include <hip/hip_bf16.h>

// Problem: B=4, T=2048, C=1024. Single-head causal attention, fp32 in/out.
// Strategy: bf16 MFMA for all matmuls. R2: fused QKV gemm (N=3072) with
// XCD-aware swizzle, compact triangular S launch, merged casts, vec softmax.

typedef short bf16x8 __attribute__((ext_vector_type(8)));
typedef float f32x4  __attribute__((ext_vector_type(4)));

#define T_SEQ 2048
#define EMB   1024
#define NBAT  4

struct alignas(8) bh4 { __hip_bfloat16 a, b, c, d; };

__device__ __forceinline__ bh4 pack4(float x, float y, float z, float w) {
    bh4 o { __float2bfloat16(x), __float2bfloat16(y),
            __float2bfloat16(z), __float2bfloat16(w) };
    return o;
}

// ---------------------------------------------------------------- casts
__global__ void cast_f32_bf16_x4(const float* __restrict__ src,
                                 __hip_bfloat16* __restrict__ dst, int n4) {
    int i = blockIdx.x * blockDim.x + threadIdx.x;
    if (i >= n4) return;
    float4 v = reinterpret_cast<const float4*>(src)[i];
    reinterpret_cast<bh4*>(dst)[i] = pack4(v.x, v.y, v.z, v.w);
}

// all three weight matrices in one dispatch; blockIdx.y selects source.
// dst rows 0-1023 = Wq, 1024-2047 = Wk, 2048-3071 = Wv  -> B[3072][1024]
__global__ void cast_w3(const float* __restrict__ w0,
                        const float* __restrict__ w1,
                        const float* __restrict__ w2,
                        __hip_bfloat16* __restrict__ dst) {
    const float* src = (blockIdx.y == 0) ? w0 : (blockIdx.y == 1) ? w1 : w2;
    int i = blockIdx.x * blockDim.x + threadIdx.x;      // 0..262143
    float4 v = reinterpret_cast<const float4*>(src)[i];
    reinterpret_cast<bh4*>(dst + (size_t)blockIdx.y * 1048576)[i] =
        pack4(v.x, v.y, v.z, v.w);
}

// ---------------------------------------------------------------- gemm_bt
// C[M,N] = A[M,K] * B[N,K]^T  (A,B row-major, K contiguous), 128x128 tile,
// 256 thr = 4 waves, each wave 64x64 via 4x4 x mfma_f32_16x16x32_bf16.
// OUT_BF16: bf16 C else fp32. KBOUND: K-loop to (rt+1)*128 (causal PV).
// SWZ: 0 = (x=ct, y=rt, z=batch)
//      1 = 1-D grid 1536, XCD-slab swizzle for fused QKV (rt slab per XCD)
//      2 = compact lower-triangle launch (x = triangular index, z = batch)
__device__ __forceinline__ void load_lds16(const void* g, void* l) {
    __builtin_amdgcn_global_load_lds(
        (const __attribute__((address_space(1))) void*)g,
        (__attribute__((address_space(3))) void*)l, 16, 0, 0);
}

template<int OUT_BF16, int KBOUND, int SWZ>
__global__ __launch_bounds__(256) void gemm_bt(
    const __hip_bfloat16* __restrict__ Abase,
    const __hip_bfloat16* __restrict__ Bbase,
    void* __restrict__ Cbase,
    int K, int lda, int ldb, int ldc,
    long batchA, long batchB, long batchC)
{
    int ct, rt, bz;
    if (SWZ == 1) {
        // blocks map to XCDs round-robin (bid % 8). Give each XCD a slab of
        // 8 row-tiles (2 MB of A, L2-resident) and sweep ct across it.
        const int bid = blockIdx.x;
        const int xcd = bid & 7;
        const int ii  = bid >> 3;            // 0..191
        rt = (xcd << 3) | (ii & 7);          // 0..63
        ct = ii >> 3;                        // 0..23
        bz = 0;
    } else if (SWZ == 2) {
        const int bid = blockIdx.x;          // 0..135
        int r = (int)((sqrtf(8.f * bid + 1.f) - 1.f) * 0.5f);
        while ((r + 1) * (r + 2) / 2 <= bid) ++r;
        while (r * (r + 1) / 2 > bid) --r;
        rt = r;
        ct = bid - r * (r + 1) / 2;
        bz = blockIdx.z;
    } else {
        ct = blockIdx.x; rt = blockIdx.y; bz = blockIdx.z;
    }
    const int k_len = KBOUND ? (rt + 1) * 128 : K;

    const short* A = (const short*)Abase + bz * batchA + (long)rt * 128 * lda;
    const short* B = (const short*)Bbase + bz * batchB + (long)ct * 128 * ldb;

    __shared__ short lsA[128 * 32];
    __shared__ short lsB[128 * 32];

    const int tid  = threadIdx.x;
    const int wave = tid >> 6;
    const int lane = tid & 63;
    const int wr   = (wave >> 1) * 64;
    const int wc   = (wave &  1) * 64;

    const int srow = wave * 32 + (lane >> 2);
    const int scol = (lane & 3) * 8;

    const int frow = lane & 15;
    const int fk   = (lane >> 4) * 8;

    f32x4 acc[4][4] = {};

    for (int k0 = 0; k0 < k_len; k0 += 32) {
        const short* ga = A + (long)srow * lda + k0 + scol;
        const short* gb = B + (long)srow * ldb + k0 + scol;
        load_lds16(ga,             &lsA[(wave * 32) * 32]);
        load_lds16(ga + 16L * lda, &lsA[(wave * 32 + 16) * 32]);
        load_lds16(gb,             &lsB[(wave * 32) * 32]);
        load_lds16(gb + 16L * ldb, &lsB[(wave * 32 + 16) * 32]);
        __syncthreads();

        bf16x8 af[4], bfr[4];
        #pragma unroll
        for (int m = 0; m < 4; ++m)
            af[m] = *(const bf16x8*)&lsA[(wr + m * 16 + frow) * 32 + fk];
        #pragma unroll
        for (int n = 0; n < 4; ++n)
            bfr[n] = *(const bf16x8*)&lsB[(wc + n * 16 + frow) * 32 + fk];
        #pragma unroll
        for (int m = 0; m < 4; ++m)
            #pragma unroll
            for (int n = 0; n < 4; ++n)
                acc[m][n] = __builtin_amdgcn_mfma_f32_16x16x32_bf16(
                    af[m], bfr[n], acc[m][n], 0, 0, 0);
        __syncthreads();
    }

    // epilogue: C/D layout col = lane&15, row = (lane>>4)*4 + reg
    const long crow0 = (long)rt * 128 + wr;
    const long ccol0 = (long)ct * 128 + wc;
    const int  orow  = (lane >> 4) * 4;
    const int  ocol  = lane & 15;

    if (OUT_BF16) {
        __hip_bfloat16* C = (__hip_bfloat16*)Cbase + bz * batchC;
        #pragma unroll
        for (int m = 0; m < 4; ++m)
            #pragma unroll
            for (int n = 0; n < 4; ++n)
                #pragma unroll
                for (int r = 0; r < 4; ++r)
                    C[(crow0 + m * 16 + orow + r) * ldc + ccol0 + n * 16 + ocol] =
                        __float2bfloat16(acc[m][n][r]);
    } else {
        float* C = (float*)Cbase + bz * batchC;
        #pragma unroll
        for (int m = 0; m < 4; ++m)
            #pragma unroll
            for (int n = 0; n < 4; ++n)
                #pragma unroll
                for (int r = 0; r < 4; ++r)
                    C[(crow0 + m * 16 + orow + r) * ldc + ccol0 + n * 16 + ocol] =
                        acc[m][n][r];
    }
}

// ---------------------------------------------------------------- V transpose
// V rows live at qkv col offset 2048, row stride 3072. vT: [B][EMB][T] bf16.
__global__ void transpose_v(const __hip_bfloat16* __restrict__ QKV,
                            __hip_bfloat16* __restrict__ vT) {
    __shared__ __hip_bfloat16 tile[64][65];
    const int b  = blockIdx.z;
    const int t0 = blockIdx.x * 64;
    const int d0 = blockIdx.y * 64;
    const int tid = threadIdx.x;           // 256
    const int c  = tid & 63;
    const int r4 = tid >> 6;
    #pragma unroll
    for (int i = 0; i < 16; ++i) {
        int row = r4 + i * 4;
        tile[row][c] = QKV[(size_t)(b * T_SEQ + t0 + row) * 3072 + 2048 + d0 + c];
    }
    __syncthreads();
    #pragma unroll
    for (int i = 0; i < 16; ++i) {
        int drow = r4 + i * 4;
        vT[((size_t)b * EMB + d0 + drow) * T_SEQ + t0 + c] = tile[c][drow];
    }
}

// ---------------------------------------------------------------- causal softmax
// In-place: fp32 S row (8 KB) -> bf16 P over the first 4 KB of the same row
// (row stride stays 8 KB => no cross-row aliasing). float4 / bh4 vectorized.
__device__ __forceinline__ float waveMax(float v) {
    #pragma unroll
    for (int o = 32; o; o >>= 1) v = fmaxf(v, __shfl_xor(v, o));
    return v;
}
__device__ __forceinline__ float waveSum(float v) {
    #pragma unroll
    for (int o = 32; o; o >>= 1) v += __shfl_xor(v, o);
    return v;
}

__global__ void softmax_causal(float* __restrict__ Sbuf) {
    const int r = blockIdx.x;              // 0 .. B*T-1
    const int t = r & (T_SEQ - 1);
    float* srow = Sbuf + (size_t)r * T_SEQ;
    const float4* srow4 = (const float4*)srow;
    const float scale = 0.03125f;          // 1024^-0.5
    const int tid  = threadIdx.x;          // 256
    const int wave = tid >> 6;
    const int lane = tid & 63;
    __shared__ float red[4];

    float4 a = srow4[tid];                 // elements 4*tid .. +3
    float4 b = srow4[tid + 256];           // elements 1024+4*tid .. +3
    const int base0 = 4 * tid;
    const int base1 = 1024 + 4 * tid;

    float v[8];
    float av[4] = {a.x, a.y, a.z, a.w};
    float bv[4] = {b.x, b.y, b.z, b.w};
    float mx = -INFINITY;
    #pragma unroll
    for (int j = 0; j < 4; ++j) {
        v[j]     = (base0 + j <= t) ? av[j] * scale : -INFINITY;
        v[4 + j] = (base1 + j <= t) ? bv[j] * scale : -INFINITY;
        mx = fmaxf(mx, fmaxf(v[j], v[4 + j]));
    }
    mx = waveMax(mx);
    if (lane == 0) red[wave] = mx;
    __syncthreads();
    mx = fmaxf(fmaxf(red[0], red[1]), fmaxf(red[2], red[3]));
    __syncthreads();

    float sum = 0.f;
    #pragma unroll
    for (int j = 0; j < 8; ++j) {
        float e = __expf(v[j] - mx);       // exp(-inf - mx) = 0
        v[j] = e;
        sum += e;
    }
    sum = waveSum(sum);
    if (lane == 0) red[wave] = sum;
    __syncthreads();
    sum = red[0] + red[1] + red[2] + red[3];
    const float inv = 1.f / sum;

    const int kend = ((t >> 7) + 1) << 7;  // round_up(t+1, 128)
    bh4* prow = (bh4*)srow;                // bf16 rows, stride 4096 shorts
    if (base0 < kend)
        prow[tid]       = pack4(v[0] * inv, v[1] * inv, v[2] * inv, v[3] * inv);
    if (base1 < kend)
        prow[tid + 256] = pack4(v[4] * inv, v[5] * inv, v[6] * inv, v[7] * inv);
}

// ---------------------------------------------------------------- launch
extern "C" void kernel_launch(void* const* d_in, const int* in_sizes, int n_in,
                              void* d_out, int out_size, void* d_ws, size_t ws_size,
                              hipStream_t stream) {
    const float* x  = (const float*)d_in[0];
    const float* Wq = (const float*)d_in[1];
    const float* Wk = (const float*)d_in[2];
    const float* Wv = (const float*)d_in[3];

    char* ws = (char*)d_ws;
    // workspace layout (bytes):
    //   xb  @ 0         : 8192*1024*2      = 16,777,216
    //   wb  @ 16777216  : 3072*1024*2      =  6,291,456
    //   qkv @ 23068672  : 8192*3072*2      = 50,331,648   (cols: Q|K|V)
    //   vT  @ 73400320  : 4*1024*2048*2    = 16,777,216
    //   S   @ 90177536  : 4*2048*2048*4    = 67,108,864   (P bf16 aliases S rows)
    // total 157,286,400
    __hip_bfloat16* xb  = (__hip_bfloat16*)(ws);
    __hip_bfloat16* wb  = (__hip_bfloat16*)(ws + 16777216);
    __hip_bfloat16* qkv = (__hip_bfloat16*)(ws + 23068672);
    __hip_bfloat16* vT  = (__hip_bfloat16*)(ws + 73400320);
    float*          S   = (float*)        (ws + 90177536);

    // 1) casts (x; then all three W in one dispatch)
    cast_f32_bf16_x4<<<dim3(8192), 256, 0, stream>>>(x, xb, 2097152);
    cast_w3<<<dim3(1024, 3), 256, 0, stream>>>(Wq, Wk, Wv, wb);

    // 2) fused QKV: [8192,3072] = xb[8192,1024] @ wb[3072,1024]^T, XCD swizzle
    gemm_bt<1, 0, 1><<<dim3(1536), 256, 0, stream>>>(
        xb, wb, qkv,
        /*K*/1024, /*lda*/1024, /*ldb*/1024, /*ldc*/3072,
        0L, 0L, 0L);

    // 3) V^T per batch (V = qkv cols 2048..3071)
    transpose_v<<<dim3(32, 16, 4), 256, 0, stream>>>(qkv, vT);

    // 4) S = Q @ K^T, compact lower-triangle launch (136 tiles/batch)
    gemm_bt<0, 0, 2><<<dim3(136, 1, 4), 256, 0, stream>>>(
        qkv, qkv + 1024, S,
        /*K*/1024, /*lda*/3072, /*ldb*/3072, /*ldc*/2048,
        /*bA*/6291456L, /*bB*/6291456L, /*bC*/4194304L);

    // 5) P = softmax(mask(S/32)) -> bf16 in place (row stride 4096 shorts)
    softmax_causal<<<dim3(NBAT * T_SEQ), 256, 0, stream>>>(S);

    // 6) O = P @ V  (B^T operand = vT; causal K-bound)
    gemm_bt<0, 1, 0><<<dim3(8, 16, 4), 256, 0, stream>>>(
        (const __hip_bfloat16*)S, vT, d_out,
        /*K*/2048, /*lda*/4096, /*ldb*/2048, /*ldc*/1024,
        /*bA*/8388608L, /*bB*/2097152L, /*bC*/2097152L);
}

// Round 3
// 268.384 us; speedup vs baseline: 1.1600x; 1.0716x over previous
//
#include <hip/hip_runtime.h>
#include <hip/hip_bf16.h>

// Problem: B=4, T=2048, C=1024. Single-head causal attention, fp32 in/out.
// bf16 MFMA for all matmuls. R3: BK=64 K-loop (two 32-k sub-tiles per
// barrier pair -> half the vmcnt(0)+s_barrier drains), merged casts,
// softmax skips causally-dead half rows.

typedef short bf16x8 __attribute__((ext_vector_type(8)));
typedef float f32x4  __attribute__((ext_vector_type(4)));

#define T_SEQ 2048
#define EMB   1024
#define NBAT  4

struct alignas(8) bh4 { __hip_bfloat16 a, b, c, d; };

__device__ __forceinline__ bh4 pack4(float x, float y, float z, float w) {
    bh4 o { __float2bfloat16(x), __float2bfloat16(y),
            __float2bfloat16(z), __float2bfloat16(w) };
    return o;
}

// ---------------------------------------------------------------- merged cast
// bid < 8192: x (2097152 float4s). else: Wq|Wk|Wv -> wb rows 0/1024/2048.
__global__ void cast_all(const float* __restrict__ x,
                         const float* __restrict__ w0,
                         const float* __restrict__ w1,
                         const float* __restrict__ w2,
                         __hip_bfloat16* __restrict__ xb,
                         __hip_bfloat16* __restrict__ wb) {
    const int bid = blockIdx.x;
    if (bid < 8192) {
        int i = bid * 256 + threadIdx.x;
        float4 v = reinterpret_cast<const float4*>(x)[i];
        reinterpret_cast<bh4*>(xb)[i] = pack4(v.x, v.y, v.z, v.w);
    } else {
        int j = bid - 8192;                       // 0..3071
        int sel = j >> 10;                        // 0..2
        const float* src = (sel == 0) ? w0 : (sel == 1) ? w1 : w2;
        int i = (j & 1023) * 256 + threadIdx.x;   // 0..262143
        float4 v = reinterpret_cast<const float4*>(src)[i];
        reinterpret_cast<bh4*>(wb + (size_t)sel * 1048576)[i] =
            pack4(v.x, v.y, v.z, v.w);
    }
}

// ---------------------------------------------------------------- gemm_bt
// C[M,N] = A[M,K] * B[N,K]^T  (A,B row-major, K contiguous), 128x128 tile,
// 256 thr = 4 waves, each wave 64x64 via 4x4 x mfma_f32_16x16x32_bf16.
// BK=64: two 32-k sub-buffers staged per barrier pair.
// OUT_BF16: bf16 C else fp32. KBOUND: K-loop to (rt+1)*128 (causal PV).
// SWZ: 0 = (x=ct, y=rt, z=batch)
//      1 = 1-D grid 1536, XCD-slab swizzle for fused QKV
//      2 = compact lower-triangle launch (x = tri index, z = batch)
__device__ __forceinline__ void load_lds16(const void* g, void* l) {
    __builtin_amdgcn_global_load_lds(
        (const __attribute__((address_space(1))) void*)g,
        (__attribute__((address_space(3))) void*)l, 16, 0, 0);
}

template<int OUT_BF16, int KBOUND, int SWZ>
__global__ __launch_bounds__(256) void gemm_bt(
    const __hip_bfloat16* __restrict__ Abase,
    const __hip_bfloat16* __restrict__ Bbase,
    void* __restrict__ Cbase,
    int K, int lda, int ldb, int ldc,
    long batchA, long batchB, long batchC)
{
    int ct, rt, bz;
    if (SWZ == 1) {
        const int bid = blockIdx.x;
        const int xcd = bid & 7;
        const int ii  = bid >> 3;            // 0..191
        rt = (xcd << 3) | (ii & 7);          // 0..63
        ct = ii >> 3;                        // 0..23
        bz = 0;
    } else if (SWZ == 2) {
        const int bid = blockIdx.x;          // 0..135
        int r = (int)((sqrtf(8.f * bid + 1.f) - 1.f) * 0.5f);
        while ((r + 1) * (r + 2) / 2 <= bid) ++r;
        while (r * (r + 1) / 2 > bid) --r;
        rt = r;
        ct = bid - r * (r + 1) / 2;
        bz = blockIdx.z;
    } else {
        ct = blockIdx.x; rt = blockIdx.y; bz = blockIdx.z;
    }
    const int k_len = KBOUND ? (rt + 1) * 128 : K;   // multiple of 128

    const short* A = (const short*)Abase + bz * batchA + (long)rt * 128 * lda;
    const short* B = (const short*)Bbase + bz * batchB + (long)ct * 128 * ldb;

    __shared__ short lsA[2][128 * 32];
    __shared__ short lsB[2][128 * 32];

    const int tid  = threadIdx.x;
    const int wave = tid >> 6;
    const int lane = tid & 63;
    const int wr   = (wave >> 1) * 64;
    const int wc   = (wave &  1) * 64;

    const int srow = wave * 32 + (lane >> 2);   // staging row
    const int scol = (lane & 3) * 8;            // staging col (shorts)

    const int frow = lane & 15;                 // fragment row
    const int fk   = (lane >> 4) * 8;           // fragment k offset

    f32x4 acc[4][4] = {};

    for (int k0 = 0; k0 < k_len; k0 += 64) {
        const short* ga = A + (long)srow * lda + k0 + scol;
        const short* gb = B + (long)srow * ldb + k0 + scol;
        load_lds16(ga,                  &lsA[0][(wave * 32) * 32]);
        load_lds16(ga + 16L * lda,      &lsA[0][(wave * 32 + 16) * 32]);
        load_lds16(ga + 32,             &lsA[1][(wave * 32) * 32]);
        load_lds16(ga + 16L * lda + 32, &lsA[1][(wave * 32 + 16) * 32]);
        load_lds16(gb,                  &lsB[0][(wave * 32) * 32]);
        load_lds16(gb + 16L * ldb,      &lsB[0][(wave * 32 + 16) * 32]);
        load_lds16(gb + 32,             &lsB[1][(wave * 32) * 32]);
        load_lds16(gb + 16L * ldb + 32, &lsB[1][(wave * 32 + 16) * 32]);
        __syncthreads();

        #pragma unroll
        for (int sub = 0; sub < 2; ++sub) {
            bf16x8 af[4], bfr[4];
            #pragma unroll
            for (int m = 0; m < 4; ++m)
                af[m] = *(const bf16x8*)&lsA[sub][(wr + m * 16 + frow) * 32 + fk];
            #pragma unroll
            for (int n = 0; n < 4; ++n)
                bfr[n] = *(const bf16x8*)&lsB[sub][(wc + n * 16 + frow) * 32 + fk];
            #pragma unroll
            for (int m = 0; m < 4; ++m)
                #pragma unroll
                for (int n = 0; n < 4; ++n)
                    acc[m][n] = __builtin_amdgcn_mfma_f32_16x16x32_bf16(
                        af[m], bfr[n], acc[m][n], 0, 0, 0);
        }
        __syncthreads();
    }

    // epilogue: C/D layout col = lane&15, row = (lane>>4)*4 + reg
    const long crow0 = (long)rt * 128 + wr;
    const long ccol0 = (long)ct * 128 + wc;
    const int  orow  = (lane >> 4) * 4;
    const int  ocol  = lane & 15;

    if (OUT_BF16) {
        __hip_bfloat16* C = (__hip_bfloat16*)Cbase + bz * batchC;
        #pragma unroll
        for (int m = 0; m < 4; ++m)
            #pragma unroll
            for (int n = 0; n < 4; ++n)
                #pragma unroll
                for (int r = 0; r < 4; ++r)
                    C[(crow0 + m * 16 + orow + r) * ldc + ccol0 + n * 16 + ocol] =
                        __float2bfloat16(acc[m][n][r]);
    } else {
        float* C = (float*)Cbase + bz * batchC;
        #pragma unroll
        for (int m = 0; m < 4; ++m)
            #pragma unroll
            for (int n = 0; n < 4; ++n)
                #pragma unroll
                for (int r = 0; r < 4; ++r)
                    C[(crow0 + m * 16 + orow + r) * ldc + ccol0 + n * 16 + ocol] =
                        acc[m][n][r];
    }
}

// ---------------------------------------------------------------- V transpose
__global__ void transpose_v(const __hip_bfloat16* __restrict__ QKV,
                            __hip_bfloat16* __restrict__ vT) {
    __shared__ __hip_bfloat16 tile[64][65];
    const int b  = blockIdx.z;
    const int t0 = blockIdx.x * 64;
    const int d0 = blockIdx.y * 64;
    const int tid = threadIdx.x;           // 256
    const int c  = tid & 63;
    const int r4 = tid >> 6;
    #pragma unroll
    for (int i = 0; i < 16; ++i) {
        int row = r4 + i * 4;
        tile[row][c] = QKV[(size_t)(b * T_SEQ + t0 + row) * 3072 + 2048 + d0 + c];
    }
    __syncthreads();
    #pragma unroll
    for (int i = 0; i < 16; ++i) {
        int drow = r4 + i * 4;
        vT[((size_t)b * EMB + d0 + drow) * T_SEQ + t0 + c] = tile[c][drow];
    }
}

// ---------------------------------------------------------------- causal softmax
__device__ __forceinline__ float waveMax(float v) {
    #pragma unroll
    for (int o = 32; o; o >>= 1) v = fmaxf(v, __shfl_xor(v, o));
    return v;
}
__device__ __forceinline__ float waveSum(float v) {
    #pragma unroll
    for (int o = 32; o; o >>= 1) v += __shfl_xor(v, o);
    return v;
}

__global__ void softmax_causal(float* __restrict__ Sbuf) {
    const int r = blockIdx.x;              // 0 .. B*T-1
    const int t = r & (T_SEQ - 1);
    float* srow = Sbuf + (size_t)r * T_SEQ;
    const float4* srow4 = (const float4*)srow;
    const float scale = 0.03125f;          // 1024^-0.5
    const int tid  = threadIdx.x;          // 256
    const int wave = tid >> 6;
    const int lane = tid & 63;
    __shared__ float red[4];

    const int kend = ((t >> 7) + 1) << 7;  // round_up(t+1, 128)
    const bool hi  = kend > 1024;          // second half live? (block-uniform)

    float4 a = srow4[tid];
    float4 b = make_float4(0.f, 0.f, 0.f, 0.f);
    if (hi) b = srow4[tid + 256];
    const int base0 = 4 * tid;
    const int base1 = 1024 + 4 * tid;

    float v[8];
    float av[4] = {a.x, a.y, a.z, a.w};
    float bv[4] = {b.x, b.y, b.z, b.w};
    float mx = -INFINITY;
    #pragma unroll
    for (int j = 0; j < 4; ++j) {
        v[j]     = (base0 + j <= t) ? av[j] * scale : -INFINITY;
        v[4 + j] = (base1 + j <= t) ? bv[j] * scale : -INFINITY;
        mx = fmaxf(mx, fmaxf(v[j], v[4 + j]));
    }
    mx = waveMax(mx);
    if (lane == 0) red[wave] = mx;
    __syncthreads();
    mx = fmaxf(fmaxf(red[0], red[1]), fmaxf(red[2], red[3]));
    __syncthreads();

    float sum = 0.f;
    #pragma unroll
    for (int j = 0; j < 8; ++j) {
        float e = __expf(v[j] - mx);       // exp(-inf - mx) = 0
        v[j] = e;
        sum += e;
    }
    sum = waveSum(sum);
    if (lane == 0) red[wave] = sum;
    __syncthreads();
    sum = red[0] + red[1] + red[2] + red[3];
    const float inv = 1.f / sum;

    bh4* prow = (bh4*)srow;                // bf16 rows, stride 4096 shorts
    if (base0 < kend)
        prow[tid]       = pack4(v[0] * inv, v[1] * inv, v[2] * inv, v[3] * inv);
    if (base1 < kend)
        prow[tid + 256] = pack4(v[4] * inv, v[5] * inv, v[6] * inv, v[7] * inv);
}

// ---------------------------------------------------------------- launch
extern "C" void kernel_launch(void* const* d_in, const int* in_sizes, int n_in,
                              void* d_out, int out_size, void* d_ws, size_t ws_size,
                              hipStream_t stream) {
    const float* x  = (const float*)d_in[0];
    const float* Wq = (const float*)d_in[1];
    const float* Wk = (const float*)d_in[2];
    const float* Wv = (const float*)d_in[3];

    char* ws = (char*)d_ws;
    // workspace layout (bytes):
    //   xb  @ 0         : 8192*1024*2      = 16,777,216
    //   wb  @ 16777216  : 3072*1024*2      =  6,291,456
    //   qkv @ 23068672  : 8192*3072*2      = 50,331,648   (cols: Q|K|V)
    //   vT  @ 73400320  : 4*1024*2048*2    = 16,777,216
    //   S   @ 90177536  : 4*2048*2048*4    = 67,108,864   (P bf16 aliases S rows)
    __hip_bfloat16* xb  = (__hip_bfloat16*)(ws);
    __hip_bfloat16* wb  = (__hip_bfloat16*)(ws + 16777216);
    __hip_bfloat16* qkv = (__hip_bfloat16*)(ws + 23068672);
    __hip_bfloat16* vT  = (__hip_bfloat16*)(ws + 73400320);
    float*          S   = (float*)        (ws + 90177536);

    // 1) all casts in one dispatch
    cast_all<<<dim3(11264), 256, 0, stream>>>(x, Wq, Wk, Wv, xb, wb);

    // 2) fused QKV: [8192,3072] = xb @ wb^T, XCD slab swizzle
    gemm_bt<1, 0, 1><<<dim3(1536), 256, 0, stream>>>(
        xb, wb, qkv,
        /*K*/1024, /*lda*/1024, /*ldb*/1024, /*ldc*/3072,
        0L, 0L, 0L);

    // 3) V^T per batch (V = qkv cols 2048..3071)
    transpose_v<<<dim3(32, 16, 4), 256, 0, stream>>>(qkv, vT);

    // 4) S = Q @ K^T, compact lower-triangle launch
    gemm_bt<0, 0, 2><<<dim3(136, 1, 4), 256, 0, stream>>>(
        qkv, qkv + 1024, S,
        /*K*/1024, /*lda*/3072, /*ldb*/3072, /*ldc*/2048,
        /*bA*/6291456L, /*bB*/6291456L, /*bC*/4194304L);

    // 5) P = softmax(mask(S/32)) -> bf16 in place (row stride 4096 shorts)
    softmax_causal<<<dim3(NBAT * T_SEQ), 256, 0, stream>>>(S);

    // 6) O = P @ V  (B^T operand = vT; causal K-bound)
    gemm_bt<0, 1, 0><<<dim3(8, 16, 4), 256, 0, stream>>>(
        (const __hip_bfloat16*)S, vT, d_out,
        /*K*/2048, /*lda*/4096, /*ldb*/2048, /*ldc*/1024,
        /*bA*/8388608L, /*bB*/2097152L, /*bC*/2097152L);
}

// Round 4
// 255.583 us; speedup vs baseline: 1.2181x; 1.0501x over previous
//
#include <hip/hip_runtime.h>
#include <hip/hip_bf16.h>

// B=4, T=2048, C=1024 single-head causal attention, fp32 in/out.
// R4: softmax folded into S-GEMM epilogue (no-max exp -> P^ bf16) + rowsum
// kernel + PV normalizes by 1/l; PV diagonal-paired blocks (uniform work);
// V-transpose folded into QKV epilogue.

typedef short bf16x8 __attribute__((ext_vector_type(8)));
typedef float f32x4  __attribute__((ext_vector_type(4)));

#define T_SEQ 2048
#define EMB   1024
#define NBAT  4

struct alignas(8) bh4 { __hip_bfloat16 a, b, c, d; };

__device__ __forceinline__ bh4 pack4(float x, float y, float z, float w) {
    bh4 o { __float2bfloat16(x), __float2bfloat16(y),
            __float2bfloat16(z), __float2bfloat16(w) };
    return o;
}

// ---------------------------------------------------------------- merged cast
__global__ void cast_all(const float* __restrict__ x,
                         const float* __restrict__ w0,
                         const float* __restrict__ w1,
                         const float* __restrict__ w2,
                         __hip_bfloat16* __restrict__ xb,
                         __hip_bfloat16* __restrict__ wb) {
    const int bid = blockIdx.x;
    if (bid < 8192) {
        int i = bid * 256 + threadIdx.x;
        float4 v = reinterpret_cast<const float4*>(x)[i];
        reinterpret_cast<bh4*>(xb)[i] = pack4(v.x, v.y, v.z, v.w);
    } else {
        int j = bid - 8192;                       // 0..3071
        int sel = j >> 10;
        const float* src = (sel == 0) ? w0 : (sel == 1) ? w1 : w2;
        int i = (j & 1023) * 256 + threadIdx.x;
        float4 v = reinterpret_cast<const float4*>(src)[i];
        reinterpret_cast<bh4*>(wb + (size_t)sel * 1048576)[i] =
            pack4(v.x, v.y, v.z, v.w);
    }
}

// ---------------------------------------------------------------- gemm_bt
// C[M,N] = A[M,K]*B[N,K]^T, 128x128 tile, 4 waves, BK=64 (2x 32-k subtiles).
// EPI: 2 = QKV split (Q/K bf16 to qk, V transposed bh4 to vT)
//      3 = P^ = exp(s/32) bf16 with causal mask
//      4 = fp32 * invl[row] to d_out
// KBOUND: k_len = (rt+1)*128.
// SWZ: 1 = XCD-slab (QKV), 2 = compact triangle, 3 = diagonal pair (PV)
__device__ __forceinline__ void load_lds16(const void* g, void* l) {
    __builtin_amdgcn_global_load_lds(
        (const __attribute__((address_space(1))) void*)g,
        (__attribute__((address_space(3))) void*)l, 16, 0, 0);
}

template<int EPI, int KBOUND, int SWZ>
__global__ __launch_bounds__(256) void gemm_bt(
    const __hip_bfloat16* __restrict__ Abase,
    const __hip_bfloat16* __restrict__ Bbase,
    void* __restrict__ Cbase,
    __hip_bfloat16* __restrict__ Vt,       // EPI=2 only
    const float* __restrict__ invl,        // EPI=4 only
    int K, int lda, int ldb, int ldc,
    long batchA, long batchB, long batchC)
{
    int ct, rt = 0, pr = 0, bz;
    if (SWZ == 1) {
        const int bid = blockIdx.x;
        const int xcd = bid & 7;
        const int ii  = bid >> 3;            // 0..191
        rt = (xcd << 3) | (ii & 7);          // 0..63
        ct = ii >> 3;                        // 0..23
        bz = 0;
    } else if (SWZ == 2) {
        const int bid = blockIdx.x;          // 0..135
        int r = (int)((sqrtf(8.f * bid + 1.f) - 1.f) * 0.5f);
        while ((r + 1) * (r + 2) / 2 <= bid) ++r;
        while (r * (r + 1) / 2 > bid) --r;
        rt = r;
        ct = bid - r * (r + 1) / 2;
        bz = blockIdx.z;
    } else {                                  // SWZ == 3
        ct = blockIdx.x;                      // 0..7
        pr = blockIdx.y;                      // 0..7
        bz = blockIdx.z;
    }

    __shared__ short lsA[2][128 * 32];
    __shared__ short lsB[2][128 * 32];

    const int tid  = threadIdx.x;
    const int wave = tid >> 6;
    const int lane = tid & 63;
    const int wr   = (wave >> 1) * 64;
    const int wc   = (wave &  1) * 64;

    const int srow = wave * 32 + (lane >> 2);
    const int scol = (lane & 3) * 8;
    const int frow = lane & 15;
    const int fk   = (lane >> 4) * 8;

    const int nleg = (SWZ == 3) ? 2 : 1;
    for (int leg = 0; leg < nleg; ++leg) {
        if (SWZ == 3) rt = (leg == 0) ? pr : 15 - pr;
        const int k_len = KBOUND ? (rt + 1) * 128 : K;

        const short* A = (const short*)Abase + bz * batchA + (long)rt * 128 * lda;
        const short* B = (const short*)Bbase + bz * batchB + (long)ct * 128 * ldb;

        f32x4 acc[4][4] = {};

        for (int k0 = 0; k0 < k_len; k0 += 64) {
            const short* ga = A + (long)srow * lda + k0 + scol;
            const short* gb = B + (long)srow * ldb + k0 + scol;
            load_lds16(ga,                  &lsA[0][(wave * 32) * 32]);
            load_lds16(ga + 16L * lda,      &lsA[0][(wave * 32 + 16) * 32]);
            load_lds16(ga + 32,             &lsA[1][(wave * 32) * 32]);
            load_lds16(ga + 16L * lda + 32, &lsA[1][(wave * 32 + 16) * 32]);
            load_lds16(gb,                  &lsB[0][(wave * 32) * 32]);
            load_lds16(gb + 16L * ldb,      &lsB[0][(wave * 32 + 16) * 32]);
            load_lds16(gb + 32,             &lsB[1][(wave * 32) * 32]);
            load_lds16(gb + 16L * ldb + 32, &lsB[1][(wave * 32 + 16) * 32]);
            __syncthreads();

            #pragma unroll
            for (int sub = 0; sub < 2; ++sub) {
                bf16x8 af[4], bfr[4];
                #pragma unroll
                for (int m = 0; m < 4; ++m)
                    af[m] = *(const bf16x8*)&lsA[sub][(wr + m * 16 + frow) * 32 + fk];
                #pragma unroll
                for (int n = 0; n < 4; ++n)
                    bfr[n] = *(const bf16x8*)&lsB[sub][(wc + n * 16 + frow) * 32 + fk];
                #pragma unroll
                for (int m = 0; m < 4; ++m)
                    #pragma unroll
                    for (int n = 0; n < 4; ++n)
                        acc[m][n] = __builtin_amdgcn_mfma_f32_16x16x32_bf16(
                            af[m], bfr[n], acc[m][n], 0, 0, 0);
            }
            __syncthreads();
        }

        // epilogue: C/D layout col = lane&15, row = (lane>>4)*4 + reg
        const long crow0 = (long)rt * 128 + wr;
        const int  orow  = (lane >> 4) * 4;
        const int  ocol  = lane & 15;

        if (EPI == 2) {
            if (ct < 16) {                        // Q|K -> qk [8192][2048] bf16
                __hip_bfloat16* C = (__hip_bfloat16*)Cbase;
                const long ccol0 = (long)ct * 128 + wc;
                #pragma unroll
                for (int m = 0; m < 4; ++m)
                    #pragma unroll
                    for (int n = 0; n < 4; ++n)
                        #pragma unroll
                        for (int r = 0; r < 4; ++r)
                            C[(crow0 + m * 16 + orow + r) * ldc + ccol0 + n * 16 + ocol] =
                                __float2bfloat16(acc[m][n][r]);
            } else {                              // V -> vT [B][EMB][T], bh4 runs
                const int b  = rt >> 4;
                const int t0 = (rt & 15) * 128 + wr;
                #pragma unroll
                for (int m = 0; m < 4; ++m) {
                    const int t = t0 + m * 16 + orow;
                    #pragma unroll
                    for (int n = 0; n < 4; ++n) {
                        const int d = (ct - 16) * 128 + wc + n * 16 + ocol;
                        *(bh4*)&Vt[((size_t)b * EMB + d) * T_SEQ + t] =
                            pack4(acc[m][n][0], acc[m][n][1], acc[m][n][2], acc[m][n][3]);
                    }
                }
            }
        } else if (EPI == 3) {                    // P^ = exp(s/32), causal mask
            __hip_bfloat16* C = (__hip_bfloat16*)Cbase + bz * batchC;
            const long ccol0 = (long)ct * 128 + wc;
            #pragma unroll
            for (int m = 0; m < 4; ++m)
                #pragma unroll
                for (int n = 0; n < 4; ++n)
                    #pragma unroll
                    for (int r = 0; r < 4; ++r) {
                        const long row = crow0 + m * 16 + orow + r;
                        const long col = ccol0 + n * 16 + ocol;
                        float p = (col <= row) ? __expf(acc[m][n][r] * 0.03125f) : 0.f;
                        C[row * ldc + col] = __float2bfloat16(p);
                    }
        } else {                                  // EPI == 4: fp32 * invl
            float* C = (float*)Cbase + bz * batchC;
            const float* il = invl + bz * T_SEQ;
            const long ccol0 = (long)ct * 128 + wc;
            #pragma unroll
            for (int m = 0; m < 4; ++m)
                #pragma unroll
                for (int r = 0; r < 4; ++r) {
                    const long row = crow0 + m * 16 + orow + r;
                    const float s = il[row];
                    #pragma unroll
                    for (int n = 0; n < 4; ++n)
                        C[row * ldc + ccol0 + n * 16 + ocol] = acc[m][n][r] * s;
                }
        }
    }
}

// ---------------------------------------------------------------- row sums
__device__ __forceinline__ float waveSum(float v) {
    #pragma unroll
    for (int o = 32; o; o >>= 1) v += __shfl_xor(v, o);
    return v;
}

__global__ void rowsum_inv(const __hip_bfloat16* __restrict__ P,
                           float* __restrict__ invl) {
    const int row  = blockIdx.x * 4 + (threadIdx.x >> 6);   // 0..8191
    const int lane = threadIdx.x & 63;
    const int t    = row & (T_SEQ - 1);
    const int kend = ((t >> 7) + 1) << 7;                    // live cols
    const uint4* pr = (const uint4*)(P + (size_t)row * T_SEQ);
    float s = 0.f;
    for (int i = lane; i < (kend >> 3); i += 64) {
        uint4 u = pr[i];
        unsigned w[4] = {u.x, u.y, u.z, u.w};
        #pragma unroll
        for (int j = 0; j < 4; ++j) {
            s += __uint_as_float(w[j] << 16);
            s += __uint_as_float(w[j] & 0xffff0000u);
        }
    }
    s = waveSum(s);
    if (lane == 0) invl[row] = 1.f / s;
}

// ---------------------------------------------------------------- launch
extern "C" void kernel_launch(void* const* d_in, const int* in_sizes, int n_in,
                              void* d_out, int out_size, void* d_ws, size_t ws_size,
                              hipStream_t stream) {
    const float* x  = (const float*)d_in[0];
    const float* Wq = (const float*)d_in[1];
    const float* Wk = (const float*)d_in[2];
    const float* Wv = (const float*)d_in[3];

    char* ws = (char*)d_ws;
    // workspace (bytes):
    //   xb   @ 0         : 8192*1024*2  = 16,777,216
    //   wb   @ 16777216  : 3072*1024*2  =  6,291,456
    //   qk   @ 23068672  : 8192*2048*2  = 33,554,432   (cols: Q|K)
    //   vT   @ 56623104  : 4*1024*2048*2= 16,777,216
    //   P    @ 73400320  : 8192*2048*2  = 33,554,432   (P^ = exp, bf16)
    //   invl @ 106954752 : 8192*4       =     32,768
    __hip_bfloat16* xb   = (__hip_bfloat16*)(ws);
    __hip_bfloat16* wb   = (__hip_bfloat16*)(ws + 16777216);
    __hip_bfloat16* qk   = (__hip_bfloat16*)(ws + 23068672);
    __hip_bfloat16* vT   = (__hip_bfloat16*)(ws + 56623104);
    __hip_bfloat16* P    = (__hip_bfloat16*)(ws + 73400320);
    float*          invl = (float*)        (ws + 106954752);

    // 1) casts
    cast_all<<<dim3(11264), 256, 0, stream>>>(x, Wq, Wk, Wv, xb, wb);

    // 2) fused QKV (Q/K -> qk, V -> vT transposed), XCD slab swizzle
    gemm_bt<2, 0, 1><<<dim3(1536), 256, 0, stream>>>(
        xb, wb, qk, vT, nullptr,
        /*K*/1024, /*lda*/1024, /*ldb*/1024, /*ldc*/2048,
        0L, 0L, 0L);

    // 3) P^ = exp(mask(QK^T)/32) bf16, compact triangle launch
    gemm_bt<3, 0, 2><<<dim3(136, 1, 4), 256, 0, stream>>>(
        qk, qk + 1024, P, nullptr, nullptr,
        /*K*/1024, /*lda*/2048, /*ldb*/2048, /*ldc*/2048,
        /*bA*/4194304L, /*bB*/4194304L, /*bC*/4194304L);

    // 4) invl = 1 / rowsum(P^)
    rowsum_inv<<<dim3(2048), 256, 0, stream>>>(P, invl);

    // 5) O = (P^ @ V) * invl ; diagonal-paired blocks (uniform K work)
    gemm_bt<4, 1, 3><<<dim3(8, 8, 4), 256, 0, stream>>>(
        P, vT, d_out, nullptr, invl,
        /*K*/2048, /*lda*/2048, /*ldb*/2048, /*ldc*/1024,
        /*bA*/4194304L, /*bB*/2097152L, /*bC*/2097152L);
}

// Round 5
// 250.493 us; speedup vs baseline: 1.2429x; 1.0203x over previous
//
#include <hip/hip_runtime.h>
#include <hip/hip_bf16.h>

// B=4, T=2048, C=1024 single-head causal attention, fp32 in/out.
// R5: QKV V-transpose epilogue via LDS (coalesced vT stores, fixes R4's
// scattered-store regression); PV reverts to 512 blocks with descending-rt
// launch order (overlap instead of sequential legs).

typedef short bf16x8 __attribute__((ext_vector_type(8)));
typedef float f32x4  __attribute__((ext_vector_type(4)));

#define T_SEQ 2048
#define EMB   1024
#define NBAT  4

struct alignas(8) bh4 { __hip_bfloat16 a, b, c, d; };

__device__ __forceinline__ bh4 pack4(float x, float y, float z, float w) {
    bh4 o { __float2bfloat16(x), __float2bfloat16(y),
            __float2bfloat16(z), __float2bfloat16(w) };
    return o;
}

// ---------------------------------------------------------------- merged cast
__global__ void cast_all(const float* __restrict__ x,
                         const float* __restrict__ w0,
                         const float* __restrict__ w1,
                         const float* __restrict__ w2,
                         __hip_bfloat16* __restrict__ xb,
                         __hip_bfloat16* __restrict__ wb) {
    const int bid = blockIdx.x;
    if (bid < 8192) {
        int i = bid * 256 + threadIdx.x;
        float4 v = reinterpret_cast<const float4*>(x)[i];
        reinterpret_cast<bh4*>(xb)[i] = pack4(v.x, v.y, v.z, v.w);
    } else {
        int j = bid - 8192;                       // 0..3071
        int sel = j >> 10;
        const float* src = (sel == 0) ? w0 : (sel == 1) ? w1 : w2;
        int i = (j & 1023) * 256 + threadIdx.x;
        float4 v = reinterpret_cast<const float4*>(src)[i];
        reinterpret_cast<bh4*>(wb + (size_t)sel * 1048576)[i] =
            pack4(v.x, v.y, v.z, v.w);
    }
}

// ---------------------------------------------------------------- gemm_bt
// C[M,N] = A[M,K]*B[N,K]^T, 128x128 tile, 4 waves, BK=64 (2x 32-k subtiles).
// EPI: 2 = QKV split (Q/K bf16 -> qk; V -> vT transposed via LDS)
//      3 = P^ = exp(s/32) bf16 with causal mask
//      4 = fp32 * invl[row] -> d_out
// KBOUND: k_len = (rt+1)*128.
// SWZ: 1 = XCD-slab (QKV), 2 = compact triangle, 3 = descending rt (PV)
__device__ __forceinline__ void load_lds16(const void* g, void* l) {
    __builtin_amdgcn_global_load_lds(
        (const __attribute__((address_space(1))) void*)g,
        (__attribute__((address_space(3))) void*)l, 16, 0, 0);
}

template<int EPI, int KBOUND, int SWZ>
__global__ __launch_bounds__(256) void gemm_bt(
    const __hip_bfloat16* __restrict__ Abase,
    const __hip_bfloat16* __restrict__ Bbase,
    void* __restrict__ Cbase,
    __hip_bfloat16* __restrict__ Vt,       // EPI=2 only
    const float* __restrict__ invl,        // EPI=4 only
    int K, int lda, int ldb, int ldc,
    long batchA, long batchB, long batchC)
{
    int ct, rt, bz;
    if (SWZ == 1) {
        const int bid = blockIdx.x;
        const int xcd = bid & 7;
        const int ii  = bid >> 3;            // 0..191
        rt = (xcd << 3) | (ii & 7);          // 0..63
        ct = ii >> 3;                        // 0..23
        bz = 0;
    } else if (SWZ == 2) {
        const int bid = blockIdx.x;          // 0..135
        int r = (int)((sqrtf(8.f * bid + 1.f) - 1.f) * 0.5f);
        while ((r + 1) * (r + 2) / 2 <= bid) ++r;
        while (r * (r + 1) / 2 > bid) --r;
        rt = r;
        ct = bid - r * (r + 1) / 2;
        bz = blockIdx.z;
    } else {                                  // SWZ == 3: big-K blocks first
        ct = blockIdx.x;
        rt = (gridDim.y - 1) - blockIdx.y;
        bz = blockIdx.z;
    }
    const int k_len = KBOUND ? (rt + 1) * 128 : K;

    // staging: sA = smem[0..8191] (2 subtiles), sB = smem[8192..16383].
    // EPI=2 additionally reuses smem as a 128x132 bf16 transpose buffer.
    __shared__ short smem[EPI == 2 ? 16896 : 16384];
    short* sA = smem;
    short* sB = smem + 8192;

    const int tid  = threadIdx.x;
    const int wave = tid >> 6;
    const int lane = tid & 63;
    const int wr   = (wave >> 1) * 64;
    const int wc   = (wave &  1) * 64;

    const int srow = wave * 32 + (lane >> 2);
    const int scol = (lane & 3) * 8;
    const int frow = lane & 15;
    const int fk   = (lane >> 4) * 8;

    const short* A = (const short*)Abase + bz * batchA + (long)rt * 128 * lda;
    const short* B = (const short*)Bbase + bz * batchB + (long)ct * 128 * ldb;

    f32x4 acc[4][4] = {};

    for (int k0 = 0; k0 < k_len; k0 += 64) {
        const short* ga = A + (long)srow * lda + k0 + scol;
        const short* gb = B + (long)srow * ldb + k0 + scol;
        load_lds16(ga,                  &sA[(wave * 32) * 32]);
        load_lds16(ga + 16L * lda,      &sA[(wave * 32 + 16) * 32]);
        load_lds16(ga + 32,             &sA[4096 + (wave * 32) * 32]);
        load_lds16(ga + 16L * lda + 32, &sA[4096 + (wave * 32 + 16) * 32]);
        load_lds16(gb,                  &sB[(wave * 32) * 32]);
        load_lds16(gb + 16L * ldb,      &sB[(wave * 32 + 16) * 32]);
        load_lds16(gb + 32,             &sB[4096 + (wave * 32) * 32]);
        load_lds16(gb + 16L * ldb + 32, &sB[4096 + (wave * 32 + 16) * 32]);
        __syncthreads();

        #pragma unroll
        for (int sub = 0; sub < 2; ++sub) {
            bf16x8 af[4], bfr[4];
            #pragma unroll
            for (int m = 0; m < 4; ++m)
                af[m] = *(const bf16x8*)&sA[sub * 4096 + (wr + m * 16 + frow) * 32 + fk];
            #pragma unroll
            for (int n = 0; n < 4; ++n)
                bfr[n] = *(const bf16x8*)&sB[sub * 4096 + (wc + n * 16 + frow) * 32 + fk];
            #pragma unroll
            for (int m = 0; m < 4; ++m)
                #pragma unroll
                for (int n = 0; n < 4; ++n)
                    acc[m][n] = __builtin_amdgcn_mfma_f32_16x16x32_bf16(
                        af[m], bfr[n], acc[m][n], 0, 0, 0);
        }
        __syncthreads();
    }

    // epilogue: C/D layout col = lane&15, row = (lane>>4)*4 + reg
    const long crow0 = (long)rt * 128 + wr;
    const int  orow  = (lane >> 4) * 4;
    const int  ocol  = lane & 15;

    if (EPI == 2) {
        if (ct < 16) {                        // Q|K -> qk [8192][2048] bf16
            __hip_bfloat16* C = (__hip_bfloat16*)Cbase;
            const long ccol0 = (long)ct * 128 + wc;
            #pragma unroll
            for (int m = 0; m < 4; ++m)
                #pragma unroll
                for (int n = 0; n < 4; ++n)
                    #pragma unroll
                    for (int r = 0; r < 4; ++r)
                        C[(crow0 + m * 16 + orow + r) * ldc + ccol0 + n * 16 + ocol] =
                            __float2bfloat16(acc[m][n][r]);
        } else {                              // V tile -> LDS [d][t] -> vT coalesced
            const int b  = rt >> 4;
            const int t0 = (rt & 15) * 128;
            const int d0 = (ct - 16) * 128;
            // stage transposed (stride 132 shorts)
            #pragma unroll
            for (int m = 0; m < 4; ++m) {
                const int t = wr + m * 16 + orow;      // 4 consecutive t at +r
                #pragma unroll
                for (int n = 0; n < 4; ++n) {
                    const int d = wc + n * 16 + ocol;
                    *(bh4*)&smem[d * 132 + t] =
                        pack4(acc[m][n][0], acc[m][n][1], acc[m][n][2], acc[m][n][3]);
                }
            }
            __syncthreads();
            // coalesced stores: 16 lanes x 16B = one 256B run per d row
            const int dd = tid >> 4;               // 0..15
            const int cc = (tid & 15) * 8;         // t chunk
            #pragma unroll
            for (int i = 0; i < 8; ++i) {
                int d = dd + i * 16;
                bf16x8 v = *(const bf16x8*)&smem[d * 132 + cc];
                *(bf16x8*)&Vt[((size_t)b * EMB + d0 + d) * T_SEQ + t0 + cc] = v;
            }
        }
    } else if (EPI == 3) {                    // P^ = exp(s/32), causal mask
        __hip_bfloat16* C = (__hip_bfloat16*)Cbase + bz * batchC;
        const long ccol0 = (long)ct * 128 + wc;
        #pragma unroll
        for (int m = 0; m < 4; ++m)
            #pragma unroll
            for (int n = 0; n < 4; ++n)
                #pragma unroll
                for (int r = 0; r < 4; ++r) {
                    const long row = crow0 + m * 16 + orow + r;
                    const long col = ccol0 + n * 16 + ocol;
                    float p = (col <= row) ? __expf(acc[m][n][r] * 0.03125f) : 0.f;
                    C[row * ldc + col] = __float2bfloat16(p);
                }
    } else {                                  // EPI == 4: fp32 * invl
        float* C = (float*)Cbase + bz * batchC;
        const float* il = invl + bz * T_SEQ;
        const long ccol0 = (long)ct * 128 + wc;
        #pragma unroll
        for (int m = 0; m < 4; ++m)
            #pragma unroll
            for (int r = 0; r < 4; ++r) {
                const long row = crow0 + m * 16 + orow + r;
                const float s = il[row];
                #pragma unroll
                for (int n = 0; n < 4; ++n)
                    C[row * ldc + ccol0 + n * 16 + ocol] = acc[m][n][r] * s;
            }
    }
}

// ---------------------------------------------------------------- row sums
__device__ __forceinline__ float waveSum(float v) {
    #pragma unroll
    for (int o = 32; o; o >>= 1) v += __shfl_xor(v, o);
    return v;
}

__global__ void rowsum_inv(const __hip_bfloat16* __restrict__ P,
                           float* __restrict__ invl) {
    const int row  = blockIdx.x * 4 + (threadIdx.x >> 6);   // 0..8191
    const int lane = threadIdx.x & 63;
    const int t    = row & (T_SEQ - 1);
    const int kend = ((t >> 7) + 1) << 7;                    // live cols
    const uint4* pr = (const uint4*)(P + (size_t)row * T_SEQ);
    float s = 0.f;
    for (int i = lane; i < (kend >> 3); i += 64) {
        uint4 u = pr[i];
        unsigned w[4] = {u.x, u.y, u.z, u.w};
        #pragma unroll
        for (int j = 0; j < 4; ++j) {
            s += __uint_as_float(w[j] << 16);
            s += __uint_as_float(w[j] & 0xffff0000u);
        }
    }
    s = waveSum(s);
    if (lane == 0) invl[row] = 1.f / s;
}

// ---------------------------------------------------------------- launch
extern "C" void kernel_launch(void* const* d_in, const int* in_sizes, int n_in,
                              void* d_out, int out_size, void* d_ws, size_t ws_size,
                              hipStream_t stream) {
    const float* x  = (const float*)d_in[0];
    const float* Wq = (const float*)d_in[1];
    const float* Wk = (const float*)d_in[2];
    const float* Wv = (const float*)d_in[3];

    char* ws = (char*)d_ws;
    // workspace (bytes):
    //   xb   @ 0         : 8192*1024*2  = 16,777,216
    //   wb   @ 16777216  : 3072*1024*2  =  6,291,456
    //   qk   @ 23068672  : 8192*2048*2  = 33,554,432   (cols: Q|K)
    //   vT   @ 56623104  : 4*1024*2048*2= 16,777,216
    //   P    @ 73400320  : 8192*2048*2  = 33,554,432   (P^ = exp, bf16)
    //   invl @ 106954752 : 8192*4       =     32,768
    __hip_bfloat16* xb   = (__hip_bfloat16*)(ws);
    __hip_bfloat16* wb   = (__hip_bfloat16*)(ws + 16777216);
    __hip_bfloat16* qk   = (__hip_bfloat16*)(ws + 23068672);
    __hip_bfloat16* vT   = (__hip_bfloat16*)(ws + 56623104);
    __hip_bfloat16* P    = (__hip_bfloat16*)(ws + 73400320);
    float*          invl = (float*)        (ws + 106954752);

    // 1) casts
    cast_all<<<dim3(11264), 256, 0, stream>>>(x, Wq, Wk, Wv, xb, wb);

    // 2) fused QKV (Q/K -> qk, V -> vT transposed via LDS), XCD slab swizzle
    gemm_bt<2, 0, 1><<<dim3(1536), 256, 0, stream>>>(
        xb, wb, qk, vT, nullptr,
        /*K*/1024, /*lda*/1024, /*ldb*/1024, /*ldc*/2048,
        0L, 0L, 0L);

    // 3) P^ = exp(mask(QK^T)/32) bf16, compact triangle launch
    gemm_bt<3, 0, 2><<<dim3(136, 1, 4), 256, 0, stream>>>(
        qk, qk + 1024, P, nullptr, nullptr,
        /*K*/1024, /*lda*/2048, /*ldb*/2048, /*ldc*/2048,
        /*bA*/4194304L, /*bB*/4194304L, /*bC*/4194304L);

    // 4) invl = 1 / rowsum(P^)
    rowsum_inv<<<dim3(2048), 256, 0, stream>>>(P, invl);

    // 5) O = (P^ @ V) * invl ; 512 blocks, big-K (rt=15) blocks launch first
    gemm_bt<4, 1, 3><<<dim3(8, 16, 4), 256, 0, stream>>>(
        P, vT, d_out, nullptr, invl,
        /*K*/2048, /*lda*/2048, /*ldb*/2048, /*ldc*/1024,
        /*bA*/4194304L, /*bB*/2097152L, /*bC*/2097152L);
}